// Round 2
// baseline (530.602 us; speedup 1.0000x reference)
//
#include <hip/hip_runtime.h>

// MHA fwd: B=4, T=2048, D=1024, H=16, DK=64.
// Dtype-adaptive: detects at runtime whether d_in tensors are f32 or bf16.
// d_in: 0=x, 1=mask(ignored), 2=wq, 3=bq, 4=wk, 5=bk, 6=wv, 7=bv, 8=wo, 9=bo

typedef short s16x8 __attribute__((ext_vector_type(8)));
typedef float f32x4 __attribute__((ext_vector_type(4)));

#define TQ 2048
#define DQ 1024

static __device__ __forceinline__ float bf2f(unsigned short u) {
    return __uint_as_float(((unsigned int)u) << 16);
}
static __device__ __forceinline__ unsigned short f2bf(float f) {
    unsigned int x = __float_as_uint(f);
    unsigned int r = x + 0x7fffu + ((x >> 16) & 1u);  // RTNE
    return (unsigned short)(r >> 16);
}

// ---- dtype detection: genuine bf16 N(0,1) data can never decode to |v|>=1e10 ----
__global__ __launch_bounds__(64) void detect_dtype(const unsigned short* __restrict__ x,
                                                   int* __restrict__ flag) {
    int lane = threadIdx.x;
    int cnt = 0;
    for (int i = 0; i < 64; ++i) {
        float v = bf2f(x[lane * 64 + i]);
        if (!(fabsf(v) < 1e10f)) cnt++;   // counts NaN/Inf/huge
    }
    unsigned long long m = __ballot(cnt > 0);
    if (lane == 0) *flag = (m != 0ull) ? 1 : 0;
}

// ---- generic convert: src (f32 or bf16 per flag) -> bf16 ----
__global__ __launch_bounds__(256) void convert_bf16(const void* __restrict__ src,
                                                    unsigned short* __restrict__ dst,
                                                    int n, const int* __restrict__ flag) {
    int i = blockIdx.x * 256 + threadIdx.x;
    if (i >= n) return;
    if (*flag) dst[i] = f2bf(((const float*)src)[i]);
    else       dst[i] = ((const unsigned short*)src)[i];
}

// ---- weight transpose (+inline convert): dst[n*1024+k] = bf16(src[k*1024+n]) ----
__global__ __launch_bounds__(256) void transpose_wt(const void* __restrict__ src,
                                                    unsigned short* __restrict__ dst,
                                                    const int* __restrict__ flag) {
    __shared__ unsigned short t[32][33];
    int f = *flag;
    int x = threadIdx.x, y = threadIdx.y;            // block (32,8)
    int n0 = blockIdx.x * 32, k0 = blockIdx.y * 32;
    for (int j = 0; j < 32; j += 8) {
        size_t idx = (size_t)(k0 + y + j) * 1024 + n0 + x;
        t[y + j][x] = f ? f2bf(((const float*)src)[idx]) : ((const unsigned short*)src)[idx];
    }
    __syncthreads();
    for (int j = 0; j < 32; j += 8) dst[(size_t)(n0 + y + j) * 1024 + k0 + x] = t[x][y + j];
}

// ---- GEMM: C[m][n] = A[m][:K] . Bt[n][:K] + bias(n) ----
// 128x128 tile, BK=32, 4 waves (2x2), each wave 4x4 of 16x16x32 MFMA.
__global__ __launch_bounds__(256) void gemm_bf16(const short* __restrict__ A,
                                                 const short* __restrict__ Bt,
                                                 void* __restrict__ C,
                                                 const unsigned short* __restrict__ bq,
                                                 const unsigned short* __restrict__ bk,
                                                 const unsigned short* __restrict__ bv,
                                                 int K, int ldc,
                                                 const int* __restrict__ flag, int f32out) {
    __shared__ __align__(16) short As[128][40];   // +8 pad
    __shared__ __align__(16) short Bs[128][40];
    int tid = threadIdx.x;
    int wid = tid >> 6, lane = tid & 63, quad = lane >> 4, l16 = lane & 15;
    int wm = wid & 1, wn = wid >> 1;
    int m0 = blockIdx.x * 128, n0 = blockIdx.y * 128;
    bool wf = f32out && (*flag != 0);

    f32x4 acc[4][4] = {};
    int row = tid >> 2, kk = (tid & 3) * 8;
    for (int k0 = 0; k0 < K; k0 += 32) {
        *(s16x8*)&As[row][kk]      = *(const s16x8*)(A  + (size_t)(m0 + row) * K      + k0 + kk);
        *(s16x8*)&As[row + 64][kk] = *(const s16x8*)(A  + (size_t)(m0 + row + 64) * K + k0 + kk);
        *(s16x8*)&Bs[row][kk]      = *(const s16x8*)(Bt + (size_t)(n0 + row) * K      + k0 + kk);
        *(s16x8*)&Bs[row + 64][kk] = *(const s16x8*)(Bt + (size_t)(n0 + row + 64) * K + k0 + kk);
        __syncthreads();
        s16x8 a[4], b[4];
        for (int i = 0; i < 4; ++i) a[i] = *(const s16x8*)&As[wm * 64 + i * 16 + l16][quad * 8];
        for (int j = 0; j < 4; ++j) b[j] = *(const s16x8*)&Bs[wn * 64 + j * 16 + l16][quad * 8];
        for (int i = 0; i < 4; ++i)
            for (int j = 0; j < 4; ++j)
                acc[i][j] = __builtin_amdgcn_mfma_f32_16x16x32_bf16(a[i], b[j], acc[i][j], 0, 0, 0);
        __syncthreads();
    }
    for (int j = 0; j < 4; ++j) {
        int col = n0 + wn * 64 + j * 16 + l16;
        const unsigned short* bptr = (col < 1024) ? bq : (col < 2048 ? bk : bv);
        float bias = bf2f(bptr[col & 1023]);
        for (int i = 0; i < 4; ++i) {
            int rbase = m0 + wm * 64 + i * 16 + quad * 4;
            for (int r = 0; r < 4; ++r) {
                float v = acc[i][j][r] + bias;
                size_t idx = (size_t)(rbase + r) * ldc + col;
                if (wf) ((float*)C)[idx] = v;
                else    ((unsigned short*)C)[idx] = f2bf(v);
            }
        }
    }
}

// ---- V transpose: Vt[(bh*64+dk)*2048 + t] = QKV[(b*T+t)*3072 + 2048 + h*64 + dk] ----
__global__ __launch_bounds__(256) void transpose_v(const short* __restrict__ qkv,
                                                   short* __restrict__ vt) {
    __shared__ __align__(16) short tile[64][72];
    int bh = blockIdx.y, b = bh >> 4, h = bh & 15;
    int t0 = blockIdx.x * 64;
    int tid = threadIdx.x;
    for (int it = 0; it < 2; ++it) {
        int idx = tid + it * 256;
        int r = idx >> 3, kk = (idx & 7) * 8;
        *(s16x8*)&tile[r][kk] =
            *(const s16x8*)(qkv + (size_t)(b * TQ + t0 + r) * 3072 + 2048 + h * 64 + kk);
    }
    __syncthreads();
    for (int it = 0; it < 2; ++it) {
        int idx = tid + it * 256;
        int dk = idx >> 3, tt = (idx & 7) * 8;
        s16x8 v;
        for (int e = 0; e < 8; ++e) v[e] = tile[tt + e][dk];
        *(s16x8*)(vt + ((size_t)bh * 64 + dk) * TQ + t0 + tt) = v;
    }
}

// ---- fused causal flash attention: grid (32,64): x = reversed q-tile, y = b*16+h ----
__global__ __launch_bounds__(256) void attn(const short* __restrict__ qkv,
                                            const short* __restrict__ vt,
                                            unsigned short* __restrict__ y) {
    __shared__ __align__(16) short Qs[64][72];
    __shared__ __align__(16) short Ks[64][72];
    __shared__ __align__(16) short Vts[64][72];
    __shared__ __align__(16) short Ps[4][16][72];
    int tid = threadIdx.x;
    int wid = tid >> 6, lane = tid & 63, quad = lane >> 4, l16 = lane & 15;
    int qi = 31 - (int)blockIdx.x;            // big tiles first
    int bh = blockIdx.y, b = bh >> 4, h = bh & 15;

    for (int it = 0; it < 2; ++it) {
        int idx = tid + it * 256;
        int r = idx >> 3, kk = (idx & 7) * 8;
        *(s16x8*)&Qs[r][kk] =
            *(const s16x8*)(qkv + (size_t)(b * TQ + qi * 64 + r) * 3072 + h * 64 + kk);
    }
    __syncthreads();
    s16x8 qf0 = *(const s16x8*)&Qs[wid * 16 + l16][quad * 8];
    s16x8 qf1 = *(const s16x8*)&Qs[wid * 16 + l16][32 + quad * 8];

    float m_old[4], l_sum[4];
    for (int r = 0; r < 4; ++r) { m_old[r] = -INFINITY; l_sum[r] = 0.f; }
    f32x4 o[4] = {};

    for (int kt = 0; kt <= qi; ++kt) {
        __syncthreads();   // previous iteration's Ks/Vts/Ps reads are done
        for (int it = 0; it < 2; ++it) {
            int idx = tid + it * 256;
            int r = idx >> 3, kk = (idx & 7) * 8;
            *(s16x8*)&Ks[r][kk] =
                *(const s16x8*)(qkv + (size_t)(b * TQ + kt * 64 + r) * 3072 + 1024 + h * 64 + kk);
            *(s16x8*)&Vts[r][kk] =
                *(const s16x8*)(vt + ((size_t)bh * 64 + r) * TQ + kt * 64 + kk);
        }
        __syncthreads();

        f32x4 s[4] = {};
        for (int j = 0; j < 4; ++j) {
            s16x8 kb0 = *(const s16x8*)&Ks[j * 16 + l16][quad * 8];
            s16x8 kb1 = *(const s16x8*)&Ks[j * 16 + l16][32 + quad * 8];
            s[j] = __builtin_amdgcn_mfma_f32_16x16x32_bf16(qf0, kb0, s[j], 0, 0, 0);
            s[j] = __builtin_amdgcn_mfma_f32_16x16x32_bf16(qf1, kb1, s[j], 0, 0, 0);
        }

        bool diag = (kt == qi);
        for (int r = 0; r < 4; ++r) {
            int qg = qi * 64 + wid * 16 + quad * 4 + r;
            float mx = -INFINITY;
            for (int j = 0; j < 4; ++j) {
                float v = s[j][r] * 0.125f;   // 1/sqrt(64)
                if (diag && (kt * 64 + j * 16 + l16) > qg) v = -INFINITY;
                s[j][r] = v;
                mx = fmaxf(mx, v);
            }
            for (int off = 1; off < 16; off <<= 1) mx = fmaxf(mx, __shfl_xor(mx, off, 64));
            float mn = fmaxf(m_old[r], mx);
            float alpha = exp2f((m_old[r] - mn) * 1.44269504f);
            float rs = 0.f;
            for (int j = 0; j < 4; ++j) {
                float pv = exp2f((s[j][r] - mn) * 1.44269504f);
                s[j][r] = pv;
                rs += pv;
            }
            for (int off = 1; off < 16; off <<= 1) rs += __shfl_xor(rs, off, 64);
            l_sum[r] = l_sum[r] * alpha + rs;
            m_old[r] = mn;
            for (int d = 0; d < 4; ++d) o[d][r] *= alpha;
            for (int j = 0; j < 4; ++j)
                Ps[wid][quad * 4 + r][j * 16 + l16] = (short)f2bf(s[j][r]);
        }
        __syncthreads();   // hardening: ensure Ps writes visible before fragment read

        s16x8 pa0 = *(const s16x8*)&Ps[wid][l16][quad * 8];
        s16x8 pa1 = *(const s16x8*)&Ps[wid][l16][32 + quad * 8];
        for (int d = 0; d < 4; ++d) {
            s16x8 vb0 = *(const s16x8*)&Vts[d * 16 + l16][quad * 8];
            s16x8 vb1 = *(const s16x8*)&Vts[d * 16 + l16][32 + quad * 8];
            o[d] = __builtin_amdgcn_mfma_f32_16x16x32_bf16(pa0, vb0, o[d], 0, 0, 0);
            o[d] = __builtin_amdgcn_mfma_f32_16x16x32_bf16(pa1, vb1, o[d], 0, 0, 0);
        }
    }

    for (int r = 0; r < 4; ++r) {
        float inv = 1.f / l_sum[r];
        int t = qi * 64 + wid * 16 + quad * 4 + r;
        for (int d = 0; d < 4; ++d)
            y[(size_t)(b * TQ + t) * DQ + h * 64 + d * 16 + l16] = f2bf(o[d][r] * inv);
    }
}

extern "C" void kernel_launch(void* const* d_in, const int* in_sizes, int n_in,
                              void* d_out, int out_size, void* d_ws, size_t ws_size,
                              hipStream_t stream) {
    (void)in_sizes; (void)n_in; (void)out_size; (void)ws_size;
    const void* x  = d_in[0];
    const void* wq = d_in[2]; const void* bq = d_in[3];
    const void* wk = d_in[4]; const void* bk = d_in[5];
    const void* wv = d_in[6]; const void* bv = d_in[7];
    const void* wo = d_in[8]; const void* bo = d_in[9];

    const size_t MB = 1024 * 1024;
    char* ws = (char*)d_ws;
    unsigned short* wT  = (unsigned short*)ws;                 // 4x[1024][1024] bf16  [0,8MB)
    short* qkv = (short*)(ws + 8 * MB);                        // [8192][3072] bf16    [8,56)
    short* vt  = (short*)(ws + 56 * MB);                       // [64][64][2048] bf16  [56,72)
    unsigned short* xb = (unsigned short*)(ws + 72 * MB);      // x as bf16 (aliases yb) [72,88)
    unsigned short* yb = (unsigned short*)(ws + 72 * MB);      // attn out (after xb dead)
    unsigned short* bb = (unsigned short*)(ws + 88 * MB);      // 4x1024 bf16 biases
    int* flag = (int*)(ws + 88 * MB + 64 * 1024);

    detect_dtype<<<1, 64, 0, stream>>>((const unsigned short*)x, flag);
    convert_bf16<<<32768, 256, 0, stream>>>(x, xb, 8388608, flag);
    convert_bf16<<<4, 256, 0, stream>>>(bq, bb,        1024, flag);
    convert_bf16<<<4, 256, 0, stream>>>(bk, bb + 1024, 1024, flag);
    convert_bf16<<<4, 256, 0, stream>>>(bv, bb + 2048, 1024, flag);
    convert_bf16<<<4, 256, 0, stream>>>(bo, bb + 3072, 1024, flag);

    dim3 tb(32, 8);
    transpose_wt<<<dim3(32, 32), tb, 0, stream>>>(wq, wT,                flag);
    transpose_wt<<<dim3(32, 32), tb, 0, stream>>>(wk, wT + 1024 * 1024,  flag);
    transpose_wt<<<dim3(32, 32), tb, 0, stream>>>(wv, wT + 2048 * 1024,  flag);
    transpose_wt<<<dim3(32, 32), tb, 0, stream>>>(wo, wT + 3072 * 1024,  flag);

    gemm_bf16<<<dim3(64, 24), 256, 0, stream>>>((const short*)xb, (const short*)wT,
                                                qkv, bb, bb + 1024, bb + 2048, 1024, 3072, flag, 0);
    transpose_v<<<dim3(32, 64), 256, 0, stream>>>(qkv, vt);
    attn<<<dim3(32, 64), 256, 0, stream>>>(qkv, vt, yb);
    gemm_bf16<<<dim3(64, 8), 256, 0, stream>>>((const short*)yb, (const short*)(wT + 3072 * 1024),
                                               d_out, bb + 3072, bb + 3072, bb + 3072,
                                               1024, 1024, flag, 1);
}